// Round 10
// baseline (793.509 us; speedup 1.0000x reference)
//
#include <hip/hip_runtime.h>
#include <hip/hip_bf16.h>

#define CIN 32
#define COUT 64
#define SEGS 4
#define SCHUNK 1024

typedef __attribute__((ext_vector_type(8))) short bf16x8;
typedef __attribute__((ext_vector_type(4))) float f32x4;

__device__ inline short bf16r(float x) {
    unsigned u = __float_as_uint(x);
    return (short)((u + 0x7FFFu + ((u >> 16) & 1u)) >> 16);
}

__device__ inline unsigned pk2(float lo, float hi) {
    __hip_bfloat162 t = __float22bfloat162_rn(make_float2(lo, hi));
    return *(unsigned*)&t;
}

// ---------------------------------------------------------------------------
// Fused prep: [0,32) pack weights | [32,32+nbm) gather out_bxyz |
// rest: 80B featb rows = 32 bf16 feats (chunks 0-3) + bf16 pb.xyz (chunk 4).
__global__ void prep_kernel(const float* __restrict__ W1,
                            const float* __restrict__ W2,
                            short* __restrict__ wpack,
                            const float4* __restrict__ bxyz4,
                            const int* __restrict__ sidx,
                            float4* __restrict__ out_bxyz,
                            const float* __restrict__ feat,
                            uint4* __restrict__ featb,
                            int M, int N, int nbm) {
    int b = blockIdx.x, tid = threadIdx.x;
    if (b < 32) {
        int t = b * 256 + tid;                 // 8192 exactly
        int e = t & 7, l = (t >> 3) & 63, f = t >> 9;
        int g = l >> 4, n16 = l & 15;
        int kc = (f & 7) >> 2, nt = f & 3;
        int k = kc * 32 + g * 8 + e;
        int n = nt * 16 + n16;
        float v;
        if (f < 8) v = (k < CIN + 3) ? W1[k * COUT + n] : 0.f;
        else       v = W2[k * COUT + n];
        wpack[t] = bf16r(v);
    } else if (b < 32 + nbm) {
        int i = (b - 32) * 256 + tid;
        if (i < M) out_bxyz[i] = bxyz4[sidx[i]];
    } else {
        int p = (b - 32 - nbm) * 256 + tid;
        if (p < N) {
            const float4* s = (const float4*)(feat + (size_t)p * CIN);
            float4 f0 = s[0], f1 = s[1], f2 = s[2], f3 = s[3];
            float4 f4 = s[4], f5 = s[5], f6 = s[6], f7 = s[7];
            float4 pb = bxyz4[p];
            uint4* d = featb + (size_t)p * 5;
            d[0] = make_uint4(pk2(f0.x, f0.y), pk2(f0.z, f0.w), pk2(f1.x, f1.y), pk2(f1.z, f1.w));
            d[1] = make_uint4(pk2(f2.x, f2.y), pk2(f2.z, f2.w), pk2(f3.x, f3.y), pk2(f3.z, f3.w));
            d[2] = make_uint4(pk2(f4.x, f4.y), pk2(f4.z, f4.w), pk2(f5.x, f5.y), pk2(f5.z, f5.w));
            d[3] = make_uint4(pk2(f6.x, f6.y), pk2(f6.z, f6.w), pk2(f7.x, f7.y), pk2(f7.z, f7.w));
            d[4] = make_uint4(pk2(pb.y, pb.z), pk2(pb.w, 0.f), 0u, 0u);
        }
    }
}

// ---------------------------------------------------------------------------
// Ticketing: one returning-atomic pass; loc[e] = within-segment position.
__global__ void histloc_kernel(const int4* __restrict__ e_new4,
                               int* __restrict__ counts,
                               int4* __restrict__ loc4, int E8) {
    int i = blockIdx.x * blockDim.x + threadIdx.x;
    if (i >= E8) return;
    int4 a = e_new4[i * 2];
    int4 b = e_new4[i * 2 + 1];
    int4 la, lb;
    la.x = atomicAdd(&counts[a.x], 1);
    la.y = atomicAdd(&counts[a.y], 1);
    la.z = atomicAdd(&counts[a.z], 1);
    la.w = atomicAdd(&counts[a.w], 1);
    lb.x = atomicAdd(&counts[b.x], 1);
    lb.y = atomicAdd(&counts[b.y], 1);
    lb.z = atomicAdd(&counts[b.z], 1);
    lb.w = atomicAdd(&counts[b.w], 1);
    loc4[i * 2]     = la;
    loc4[i * 2 + 1] = lb;
}

// ---------------------------------------------------------------------------
// Scan of per-seg TILE counts -> padded tile starts; zero empty-seg outputs.
__global__ void scanA_kernel(const int* __restrict__ counts,
                             int* __restrict__ row1,
                             int* __restrict__ sums,
                             float4* __restrict__ out_feat4, int M) {
    __shared__ int lds[256];
    int t = threadIdx.x, blk = blockIdx.x;
    int base = blk * SCHUNK + t * 4;
    int c0 = (base + 0 < M) ? counts[base + 0] : 1;
    int c1 = (base + 1 < M) ? counts[base + 1] : 1;
    int c2 = (base + 2 < M) ? counts[base + 2] : 1;
    int c3 = (base + 3 < M) ? counts[base + 3] : 1;
    float4 z = make_float4(0.f, 0.f, 0.f, 0.f);
    if (c0 == 0) { float4* o = out_feat4 + (size_t)(base + 0) * 16;
#pragma unroll
        for (int i = 0; i < 16; ++i) o[i] = z; }
    if (c1 == 0) { float4* o = out_feat4 + (size_t)(base + 1) * 16;
#pragma unroll
        for (int i = 0; i < 16; ++i) o[i] = z; }
    if (c2 == 0) { float4* o = out_feat4 + (size_t)(base + 2) * 16;
#pragma unroll
        for (int i = 0; i < 16; ++i) o[i] = z; }
    if (c3 == 0) { float4* o = out_feat4 + (size_t)(base + 3) * 16;
#pragma unroll
        for (int i = 0; i < 16; ++i) o[i] = z; }
    int v0 = (base + 0 < M) ? (c0 + 15) >> 4 : 0;
    int v1 = (base + 1 < M) ? (c1 + 15) >> 4 : 0;
    int v2 = (base + 2 < M) ? (c2 + 15) >> 4 : 0;
    int v3 = (base + 3 < M) ? (c3 + 15) >> 4 : 0;
    int s = v0 + v1 + v2 + v3;
    int val = s;
    lds[t] = val; __syncthreads();
    for (int off = 1; off < 256; off <<= 1) {
        int x = (t >= off) ? lds[t - off] : 0;
        __syncthreads();
        val += x; lds[t] = val;
        __syncthreads();
    }
    int ex = val - s;
    if (base + 0 < M) row1[base + 0] = ex + v0;
    if (base + 1 < M) row1[base + 1] = ex + v0 + v1;
    if (base + 2 < M) row1[base + 2] = ex + v0 + v1 + v2;
    if (base + 3 < M) row1[base + 3] = ex + s;
    if (t == 255) sums[blk] = val;
}

// scanC with scanB folded in (nchunks<=256).
__global__ void scanC_kernel(int* __restrict__ row1,
                             const int* __restrict__ sums,
                             int* __restrict__ tstart, int M) {
    __shared__ int lds[256];
    int blk = blockIdx.x, t = threadIdx.x;
    lds[t] = (t < blk) ? sums[t] : 0;
    __syncthreads();
    for (int off = 128; off > 0; off >>= 1) {
        if (t < off) lds[t] += lds[t + off];
        __syncthreads();
    }
    int off0 = lds[0];
    if (blk == 0 && t == 0) tstart[0] = 0;
    int base = blk * SCHUNK + t * 4;
#pragma unroll
    for (int i = 0; i < 4; ++i)
        if (base + i < M) row1[base + i] += off0;
}

// ---------------------------------------------------------------------------
// Pure placement: no atomics, no pad loops.
__global__ void place_kernel(const int4* __restrict__ e_new4,
                             const int4* __restrict__ e_point4,
                             const int4* __restrict__ loc4,
                             const int* __restrict__ tstart,
                             int* __restrict__ csr_ep, int E8) {
    int i = blockIdx.x * blockDim.x + threadIdx.x;
    if (i >= E8) return;
    int4 n0 = e_new4[i * 2],   n1 = e_new4[i * 2 + 1];
    int4 p0 = e_point4[i * 2], p1 = e_point4[i * 2 + 1];
    int4 l0 = loc4[i * 2],     l1 = loc4[i * 2 + 1];
    csr_ep[tstart[n0.x] * 16 + l0.x] = p0.x;
    csr_ep[tstart[n0.y] * 16 + l0.y] = p0.y;
    csr_ep[tstart[n0.z] * 16 + l0.z] = p0.z;
    csr_ep[tstart[n0.w] * 16 + l0.w] = p0.w;
    csr_ep[tstart[n1.x] * 16 + l1.x] = p1.x;
    csr_ep[tstart[n1.y] * 16 + l1.y] = p1.y;
    csr_ep[tstart[n1.z] * 16 + l1.z] = p1.z;
    csr_ep[tstart[n1.w] * 16 + l1.w] = p1.w;
}

// Parallel pad + meta fill over segments (after place).
__global__ void padfill_kernel(const int* __restrict__ counts,
                               const int* __restrict__ tstart,
                               int* __restrict__ csr_ep,
                               int* __restrict__ tile_meta, int M) {
    int s = blockIdx.x * blockDim.x + threadIdx.x;
    if (s >= M) return;
    int cnt = counts[s];
    if (cnt == 0) return;
    int tst  = tstart[s];
    int ntl  = (cnt + 15) >> 4;
    int prow = tst * 16;
    int ep0  = csr_ep[prow];
    for (int j = cnt; j < ntl * 16; ++j) csr_ep[prow + j] = ep0;
    for (int j = 0; j < ntl; ++j)
        tile_meta[tst + j] = (s << 1) | (j == ntl - 1);
}

// ---------------------------------------------------------------------------
// Aggregation: flat padded-tile stream per wave, 2-slot ping-pong prefetch.
// w2 B-fragments in block-shared LDS (saves 32 VGPR); w1 in VGPR.
// Swizzle X(row)=(row&7)<<4 (R4/R9-verified low-conflict pattern).
__global__ __launch_bounds__(256, 6)
void agg_kernel(const uint4* __restrict__ featb,    // [N][5] chunks
                const int* __restrict__ csr_ep,     // padded
                const int* __restrict__ tstart,     // [M+1]
                const int* __restrict__ tile_meta,  // (seg<<1)|last
                const bf16x8* __restrict__ wpack,
                const float* __restrict__ b1,
                const float* __restrict__ b2,
                const float* __restrict__ W1,
                const float4* __restrict__ new_bxyz4,
                float* __restrict__ out_feat, int M) {
    __shared__ char   h1buf[4][4096];
    __shared__ bf16x8 w2lds[512];     // 8 KB, block-shared
    const int lane = threadIdx.x & 63;
    const int w    = threadIdx.x >> 6;
    const int m    = lane & 15;
    const int g    = lane >> 4;

    // block-shared w2 copy (frags 512..1023 of wpack), one barrier
    w2lds[threadIdx.x]       = wpack[512 + threadIdx.x];
    w2lds[threadIdx.x + 256] = wpack[768 + threadIdx.x];
    __syncthreads();

    int s0 = (blockIdx.x * 4 + w) * SEGS;
    if (s0 >= M) return;
    int s1 = min(s0 + SEGS, M);
    int tb = tstart[s0], te = tstart[s1];
    int n = te - tb;
    if (n <= 0) return;

    bf16x8 w1b[8];
#pragma unroll
    for (int f = 0; f < 8; ++f) w1b[f] = wpack[f * 64 + lane];

    float b1v[4], b2v[4], w1r0[4], w1r1[4], w1r2[4];
#pragma unroll
    for (int nt = 0; nt < 4; ++nt) {
        int col = nt * 16 + m;
        b1v[nt]  = b1[col];
        b2v[nt]  = b2[col];
        w1r0[nt] = W1[32 * COUT + col];
        w1r1[nt] = W1[33 * COUT + col];
        w1r2[nt] = W1[34 * COUT + col];
    }

    char* h1p = h1buf[w];
    int wA[8];
#pragma unroll
    for (int q = 0; q < 4; ++q) {
        int row = g * 4 + q;
        int kk = (row & 7) << 4;
        wA[q * 2 + 0] = (row * 256 + m * 4) ^ kk;
        wA[q * 2 + 1] = (row * 256 + (m + 16) * 4) ^ kk;
    }
    const int frm = (m & 7) << 4;
    const int rb0 = (m * 256 + g * 32) ^ frm;
    const int rb1 = (m * 256 + g * 32 + 16) ^ frm;

    f32x4 accv = {0.f, 0.f, 0.f, 0.f};

    int meta0, meta1;
    bf16x8 a10, a11;
    unsigned c4x0, c4y0, c4x1, c4y1;
    float be0[4], be1[4];

#define LOADSLOT(S, TI)                                                       \
    do {                                                                      \
        int ti_ = (TI);                                                       \
        meta##S = tile_meta[ti_];                                             \
        int ep_ = csr_ep[ti_ * 16 + m];                                       \
        const uint4* fr_ = featb + (size_t)(unsigned)ep_ * 5;                 \
        a1##S = ((const bf16x8*)fr_)[g];                                      \
        uint2 c_ = *(const uint2*)(fr_ + 4);                                  \
        c4x##S = c_.x; c4y##S = c_.y;                                         \
        float4 nb_ = new_bxyz4[meta##S >> 1];                                 \
        _Pragma("unroll")                                                     \
        for (int nt = 0; nt < 4; ++nt)                                        \
            be##S[nt] = b1v[nt] - nb_.y * w1r0[nt] - nb_.z * w1r1[nt]         \
                                 - nb_.w * w1r2[nt];                          \
    } while (0)

#define COMPUTE(S)                                                            \
    do {                                                                      \
        bool lastT = meta##S & 1;                                             \
        int  segv  = meta##S >> 1;                                            \
        bf16x8 a2 = {0, 0, 0, 0, 0, 0, 0, 0};                                 \
        if (g == 0) {                                                         \
            a2[0] = (short)(c4x##S & 0xffffu);                                \
            a2[1] = (short)(c4x##S >> 16);                                    \
            a2[2] = (short)(c4y##S & 0xffffu);                                \
        }                                                                     \
        _Pragma("unroll")                                                     \
        for (int nt = 0; nt < 4; ++nt) {                                      \
            float be = be##S[nt];                                             \
            f32x4 cc = {be, be, be, be};                                      \
            cc = __builtin_amdgcn_mfma_f32_16x16x32_bf16(a1##S, w1b[nt], cc, 0, 0, 0); \
            cc = __builtin_amdgcn_mfma_f32_16x16x32_bf16(a2, w1b[4 + nt], cc, 0, 0, 0); \
            _Pragma("unroll")                                                 \
            for (int q = 0; q < 4; ++q)                                       \
                *(float*)(h1p + wA[q * 2 + (nt & 1)] + (nt >> 1) * 128) =     \
                    fmaxf(cc[q], 0.f);                                        \
        }                                                                     \
        float4 q0 = *(const float4*)(h1p + rb0);                              \
        float4 q1 = *(const float4*)(h1p + rb1);                              \
        float4 q2 = *(const float4*)(h1p + rb0 + 128);                        \
        float4 q3 = *(const float4*)(h1p + rb1 + 128);                        \
        union { bf16x8 v; unsigned u[4]; } A30, A31;                          \
        A30.u[0] = pk2(q0.x, q0.y); A30.u[1] = pk2(q0.z, q0.w);               \
        A30.u[2] = pk2(q1.x, q1.y); A30.u[3] = pk2(q1.z, q1.w);               \
        A31.u[0] = pk2(q2.x, q2.y); A31.u[1] = pk2(q2.z, q2.w);               \
        A31.u[2] = pk2(q3.x, q3.y); A31.u[3] = pk2(q3.z, q3.w);               \
        _Pragma("unroll")                                                     \
        for (int nt = 0; nt < 4; ++nt) {                                      \
            bf16x8 wf0 = w2lds[nt * 64 + lane];                               \
            bf16x8 wf1 = w2lds[(4 + nt) * 64 + lane];                         \
            f32x4 cc = {b2v[nt], b2v[nt], b2v[nt], b2v[nt]};                  \
            cc = __builtin_amdgcn_mfma_f32_16x16x32_bf16(A30.v, wf0, cc, 0, 0, 0); \
            cc = __builtin_amdgcn_mfma_f32_16x16x32_bf16(A31.v, wf1, cc, 0, 0, 0); \
            float t2 = fmaxf(fmaxf(cc[0], cc[1]), fmaxf(cc[2], cc[3]));       \
            accv[nt] = fmaxf(accv[nt], t2);                                   \
        }                                                                     \
        if (lastT) {                                                          \
            _Pragma("unroll")                                                 \
            for (int nt = 0; nt < 4; ++nt) {                                  \
                float v = accv[nt];                                           \
                v = fmaxf(v, __shfl_xor(v, 16));                              \
                v = fmaxf(v, __shfl_xor(v, 32));                              \
                accv[nt] = v;                                                 \
            }                                                                 \
            float outv = (g == 0) ? accv[0] : (g == 1) ? accv[1]              \
                       : (g == 2) ? accv[2] : accv[3];                        \
            out_feat[(size_t)segv * COUT + lane] = outv;                      \
            accv[0] = accv[1] = accv[2] = accv[3] = 0.f;                      \
        }                                                                     \
    } while (0)

    LOADSLOT(0, tb);
    int i = 0;
    for (;;) {
        if (i >= n) break;
        if (i + 1 < n) LOADSLOT(1, tb + i + 1);
        COMPUTE(0); ++i;
        if (i >= n) break;
        if (i + 1 < n) LOADSLOT(0, tb + i + 1);
        COMPUTE(1); ++i;
    }
#undef LOADSLOT
#undef COMPUTE
}

// ---------------------------------------------------------------------------
extern "C" void kernel_launch(void* const* d_in, const int* in_sizes, int n_in,
                              void* d_out, int out_size, void* d_ws, size_t ws_size,
                              hipStream_t stream) {
    const float* bxyz   = (const float*)d_in[0];
    const float* feat   = (const float*)d_in[1];
    const int*   sidx   = (const int*)d_in[2];
    const int*   e_pt   = (const int*)d_in[3];
    const int*   e_new  = (const int*)d_in[4];
    const float* W1     = (const float*)d_in[5];
    const float* b1     = (const float*)d_in[6];
    const float* W2     = (const float*)d_in[7];
    const float* b2     = (const float*)d_in[8];

    const int N = in_sizes[0] / 4;
    const int M = in_sizes[2];
    const int E = in_sizes[3];

    float* out_bxyz = (float*)d_out;                 // [M][4]
    float* out_feat = out_bxyz + (size_t)M * 4;      // [M][64]

    // ws layout (16B aligned regions)
    char*  ws        = (char*)d_ws;
    short* wpack     = (short*)ws;                                    // 16 KiB
    size_t off_cnt   = 16384;
    int*   counts    = (int*)(ws + off_cnt);                          // M
    size_t off_ts    = off_cnt + (((size_t)M * 4 + 15) & ~(size_t)15);
    int*   tstart    = (int*)(ws + off_ts);                           // M+4
    size_t off_sums  = off_ts + ((((size_t)M + 4) * 4 + 15) & ~(size_t)15);
    int*   sums      = (int*)(ws + off_sums);                         // 256
    size_t off_loc   = off_sums + 1024;
    int*   loc       = (int*)(ws + off_loc);                          // E
    size_t off_csr   = off_loc + (size_t)E * 4;
    size_t csr_cap   = (size_t)E + 15 * (size_t)M + 64;               // padded
    int*   csr_ep    = (int*)(ws + off_csr);
    size_t off_meta  = off_csr + csr_cap * 4;
    int*   tile_meta = (int*)(ws + off_meta);                         // csr_cap/16
    size_t off_fb    = (off_meta + (csr_cap / 16 + 64) * 4 + 63) & ~(size_t)63;
    uint4* featb     = (uint4*)(ws + off_fb);                         // N*80B
    int*   row1      = tstart + 1;

    int nbm     = (M + 255) / 256;
    int nbp     = (N + 255) / 256;
    int nchunks = (M + SCHUNK - 1) / SCHUNK;   // 123 for M=125000 (<=256 req.)
    int E8      = E / 8;

    hipMemsetAsync(counts, 0, (size_t)M * 4, stream);

    prep_kernel<<<32 + nbm + nbp, 256, 0, stream>>>(
        W1, W2, wpack, (const float4*)bxyz, sidx, (float4*)out_bxyz,
        feat, featb, M, N, nbm);

    histloc_kernel<<<(E8 + 255) / 256, 256, 0, stream>>>(
        (const int4*)e_new, counts, (int4*)loc, E8);
    scanA_kernel<<<nchunks, 256, 0, stream>>>(
        counts, row1, sums, (float4*)out_feat, M);
    scanC_kernel<<<nchunks, 256, 0, stream>>>(row1, sums, tstart, M);
    place_kernel<<<(E8 + 255) / 256, 256, 0, stream>>>(
        (const int4*)e_new, (const int4*)e_pt, (const int4*)loc,
        tstart, csr_ep, E8);
    padfill_kernel<<<(M + 255) / 256, 256, 0, stream>>>(
        counts, tstart, csr_ep, tile_meta, M);

    int nblocks = (M + 4 * SEGS - 1) / (4 * SEGS);
    agg_kernel<<<nblocks, 256, 0, stream>>>(
        featb, csr_ep, tstart, tile_meta, (const bf16x8*)wpack,
        b1, b2, W1, (const float4*)out_bxyz, out_feat, M);
}

// Round 11
// 282.625 us; speedup vs baseline: 2.8076x; 2.8076x over previous
//
#include <hip/hip_runtime.h>
#include <hip/hip_bf16.h>

#define CIN 32
#define COUT 64
#define SCHUNK 1024
#define T_TILES 8

typedef __attribute__((ext_vector_type(8))) short bf16x8;
typedef __attribute__((ext_vector_type(4))) float f32x4;

__device__ inline short bf16r(float x) {
    unsigned u = __float_as_uint(x);
    return (short)((u + 0x7FFFu + ((u >> 16) & 1u)) >> 16);
}

__device__ inline unsigned pk2(float lo, float hi) {
    __hip_bfloat162 t = __float22bfloat162_rn(make_float2(lo, hi));
    return *(unsigned*)&t;
}

// ---------------------------------------------------------------------------
// Fused prep: [0,nbh) histloc ticketing | [+32) pack weights |
// [+nbm) gather out_bxyz | [+nbp) featb 80B rows (32 bf16 feat + bf16 pb.xyz).
__global__ void prep_kernel(const int4* __restrict__ e_new4,
                            int* __restrict__ counts,
                            int4* __restrict__ loc4, int E8,
                            const float* __restrict__ W1,
                            const float* __restrict__ W2,
                            short* __restrict__ wpack,
                            const float4* __restrict__ bxyz4,
                            const int* __restrict__ sidx,
                            float4* __restrict__ out_bxyz,
                            const float* __restrict__ feat,
                            uint4* __restrict__ featb,
                            int M, int N, int nbh, int nbm) {
    int b = blockIdx.x, tid = threadIdx.x;
    if (b < nbh) {
        int i = b * 256 + tid;
        if (i >= E8) return;
        int4 a = e_new4[i * 2];
        int4 c = e_new4[i * 2 + 1];
        int4 la, lb;
        la.x = atomicAdd(&counts[a.x], 1);
        la.y = atomicAdd(&counts[a.y], 1);
        la.z = atomicAdd(&counts[a.z], 1);
        la.w = atomicAdd(&counts[a.w], 1);
        lb.x = atomicAdd(&counts[c.x], 1);
        lb.y = atomicAdd(&counts[c.y], 1);
        lb.z = atomicAdd(&counts[c.z], 1);
        lb.w = atomicAdd(&counts[c.w], 1);
        loc4[i * 2]     = la;
        loc4[i * 2 + 1] = lb;
    } else if (b < nbh + 32) {
        int t = (b - nbh) * 256 + tid;         // 8192 exactly
        int e = t & 7, l = (t >> 3) & 63, f = t >> 9;
        int g = l >> 4, n16 = l & 15;
        int kc = (f & 7) >> 2, nt = f & 3;
        int k = kc * 32 + g * 8 + e;
        int n = nt * 16 + n16;
        float v;
        if (f < 8) v = (k < CIN + 3) ? W1[k * COUT + n] : 0.f;
        else       v = W2[k * COUT + n];
        wpack[t] = bf16r(v);
    } else if (b < nbh + 32 + nbm) {
        int i = (b - nbh - 32) * 256 + tid;
        if (i < M) out_bxyz[i] = bxyz4[sidx[i]];
    } else {
        int p = (b - nbh - 32 - nbm) * 256 + tid;
        if (p < N) {
            const float4* s = (const float4*)(feat + (size_t)p * CIN);
            float4 f0 = s[0], f1 = s[1], f2 = s[2], f3 = s[3];
            float4 f4 = s[4], f5 = s[5], f6 = s[6], f7 = s[7];
            float4 pb = bxyz4[p];
            uint4* d = featb + (size_t)p * 5;
            d[0] = make_uint4(pk2(f0.x, f0.y), pk2(f0.z, f0.w), pk2(f1.x, f1.y), pk2(f1.z, f1.w));
            d[1] = make_uint4(pk2(f2.x, f2.y), pk2(f2.z, f2.w), pk2(f3.x, f3.y), pk2(f3.z, f3.w));
            d[2] = make_uint4(pk2(f4.x, f4.y), pk2(f4.z, f4.w), pk2(f5.x, f5.y), pk2(f5.z, f5.w));
            d[3] = make_uint4(pk2(f6.x, f6.y), pk2(f6.z, f6.w), pk2(f7.x, f7.y), pk2(f7.z, f7.w));
            d[4] = make_uint4(pk2(pb.y, pb.z), pk2(pb.w, 0.f), 0u, 0u);
        }
    }
}

// ---------------------------------------------------------------------------
// Scan of per-seg TILE counts ((cnt+15)/16) -> padded tile starts.
__global__ void scanA_kernel(const int* __restrict__ counts,
                             int* __restrict__ row1,
                             int* __restrict__ sums, int M) {
    __shared__ int lds[256];
    int t = threadIdx.x, blk = blockIdx.x;
    int base = blk * SCHUNK + t * 4;
    int v0 = (base + 0 < M) ? (counts[base + 0] + 15) >> 4 : 0;
    int v1 = (base + 1 < M) ? (counts[base + 1] + 15) >> 4 : 0;
    int v2 = (base + 2 < M) ? (counts[base + 2] + 15) >> 4 : 0;
    int v3 = (base + 3 < M) ? (counts[base + 3] + 15) >> 4 : 0;
    int s = v0 + v1 + v2 + v3;
    int val = s;
    lds[t] = val; __syncthreads();
    for (int off = 1; off < 256; off <<= 1) {
        int x = (t >= off) ? lds[t - off] : 0;
        __syncthreads();
        val += x; lds[t] = val;
        __syncthreads();
    }
    int ex = val - s;
    if (base + 0 < M) row1[base + 0] = ex + v0;
    if (base + 1 < M) row1[base + 1] = ex + v0 + v1;
    if (base + 2 < M) row1[base + 2] = ex + v0 + v1 + v2;
    if (base + 3 < M) row1[base + 3] = ex + s;
    if (t == 255) sums[blk] = val;
}

// scanC with scanB folded in (nchunks<=256).
__global__ void scanC_kernel(int* __restrict__ row1,
                             const int* __restrict__ sums,
                             int* __restrict__ tstart, int M) {
    __shared__ int lds[256];
    int blk = blockIdx.x, t = threadIdx.x;
    lds[t] = (t < blk) ? sums[t] : 0;
    __syncthreads();
    for (int off = 128; off > 0; off >>= 1) {
        if (t < off) lds[t] += lds[t + off];
        __syncthreads();
    }
    int off0 = lds[0];
    if (blk == 0 && t == 0) tstart[0] = 0;
    int base = blk * SCHUNK + t * 4;
#pragma unroll
    for (int i = 0; i < 4; ++i)
        if (base + i < M) row1[base + i] += off0;
}

// ---------------------------------------------------------------------------
// Pure placement: no atomics.
__global__ void place_kernel(const int4* __restrict__ e_new4,
                             const int4* __restrict__ e_point4,
                             const int4* __restrict__ loc4,
                             const int* __restrict__ tstart,
                             int* __restrict__ csr_ep, int E8) {
    int i = blockIdx.x * blockDim.x + threadIdx.x;
    if (i >= E8) return;
    int4 n0 = e_new4[i * 2],   n1 = e_new4[i * 2 + 1];
    int4 p0 = e_point4[i * 2], p1 = e_point4[i * 2 + 1];
    int4 l0 = loc4[i * 2],     l1 = loc4[i * 2 + 1];
    csr_ep[tstart[n0.x] * 16 + l0.x] = p0.x;
    csr_ep[tstart[n0.y] * 16 + l0.y] = p0.y;
    csr_ep[tstart[n0.z] * 16 + l0.z] = p0.z;
    csr_ep[tstart[n0.w] * 16 + l0.w] = p0.w;
    csr_ep[tstart[n1.x] * 16 + l1.x] = p1.x;
    csr_ep[tstart[n1.y] * 16 + l1.y] = p1.y;
    csr_ep[tstart[n1.z] * 16 + l1.z] = p1.z;
    csr_ep[tstart[n1.w] * 16 + l1.w] = p1.w;
}

// Parallel pad + per-tile segment-id fill.
__global__ void padfill_kernel(const int* __restrict__ counts,
                               const int* __restrict__ tstart,
                               int* __restrict__ csr_ep,
                               int* __restrict__ tile_seg, int M) {
    int s = blockIdx.x * blockDim.x + threadIdx.x;
    if (s >= M) return;
    int cnt = counts[s];
    if (cnt == 0) return;
    int tst  = tstart[s];
    int ntl  = (cnt + 15) >> 4;
    int prow = tst * 16;
    int ep0  = csr_ep[prow];
    for (int j = cnt; j < ntl * 16; ++j) csr_ep[prow + j] = ep0;
    for (int j = 0; j < ntl; ++j) tile_seg[tst + j] = s;
}

// ---------------------------------------------------------------------------
// Aggregation: wave wid owns tiles [wid*T, wid*T+T). Tiles are INDEPENDENT:
// each ends with a per-channel atomicMax into the pre-zeroed output, so
// clamped duplicate tiles are idempotent (no validity flags, perfect balance).
// 3-slot rotating prefetch; w2 fragments in block-shared LDS; transpose
// swizzle X(row)=(row&7)<<4 (verified low-conflict).
__global__ __launch_bounds__(256)
void agg_kernel(const uint4* __restrict__ featb,    // [N][5] chunks
                const int* __restrict__ csr_ep,     // padded
                const int* __restrict__ tile_seg,   // [ntiles]
                const int* __restrict__ ntiles_ptr, // = &tstart[M]
                const bf16x8* __restrict__ wpack,
                const float* __restrict__ b1,
                const float* __restrict__ b2,
                const float* __restrict__ W1,
                const float4* __restrict__ new_bxyz4,
                float* __restrict__ out_feat) {
    __shared__ char   h1buf[4][4096];
    __shared__ bf16x8 w2lds[512];     // 8 KB block-shared

    const int ntiles = ntiles_ptr[0];
    if (blockIdx.x * 4 * T_TILES >= ntiles) return;   // whole block idle

    w2lds[threadIdx.x]       = wpack[512 + threadIdx.x];
    w2lds[threadIdx.x + 256] = wpack[768 + threadIdx.x];
    __syncthreads();

    const int lane = threadIdx.x & 63;
    const int w    = threadIdx.x >> 6;
    const int m    = lane & 15;
    const int g    = lane >> 4;

    int wid = blockIdx.x * 4 + w;
    int t0  = wid * T_TILES;
    int niter = min(T_TILES, ntiles - t0);
    if (niter <= 0) return;

    bf16x8 w1b[8];
#pragma unroll
    for (int f = 0; f < 8; ++f) w1b[f] = wpack[f * 64 + lane];

    float b1v[4], b2v[4], w1r0[4], w1r1[4], w1r2[4];
#pragma unroll
    for (int nt = 0; nt < 4; ++nt) {
        int col = nt * 16 + m;
        b1v[nt]  = b1[col];
        b2v[nt]  = b2[col];
        w1r0[nt] = W1[32 * COUT + col];
        w1r1[nt] = W1[33 * COUT + col];
        w1r2[nt] = W1[34 * COUT + col];
    }

    char* h1p = h1buf[w];
    int wA[8];
#pragma unroll
    for (int q = 0; q < 4; ++q) {
        int row = g * 4 + q;
        int kk = (row & 7) << 4;
        wA[q * 2 + 0] = (row * 256 + m * 4) ^ kk;
        wA[q * 2 + 1] = (row * 256 + (m + 16) * 4) ^ kk;
    }
    const int frm = (m & 7) << 4;
    const int rb0 = (m * 256 + g * 32) ^ frm;
    const int rb1 = (m * 256 + g * 32 + 16) ^ frm;

    int* outI = (int*)out_feat;

    int seg0, seg1, seg2;
    bf16x8 a10, a11, a12;
    unsigned c4x0, c4y0, c4x1, c4y1, c4x2, c4y2;
    float be0[4], be1[4], be2[4];

#define LOADSLOT(S, TI)                                                       \
    do {                                                                      \
        int ti_ = min((TI), ntiles - 1);                                      \
        seg##S = tile_seg[ti_];                                               \
        int ep_ = csr_ep[ti_ * 16 + m];                                       \
        const uint4* fr_ = featb + (size_t)(unsigned)ep_ * 5;                 \
        a1##S = ((const bf16x8*)fr_)[g];                                      \
        uint2 c_ = *(const uint2*)(fr_ + 4);                                  \
        c4x##S = c_.x; c4y##S = c_.y;                                         \
        float4 nb_ = new_bxyz4[seg##S];                                       \
        _Pragma("unroll")                                                     \
        for (int nt = 0; nt < 4; ++nt)                                        \
            be##S[nt] = b1v[nt] - nb_.y * w1r0[nt] - nb_.z * w1r1[nt]         \
                                 - nb_.w * w1r2[nt];                          \
    } while (0)

#define COMPUTE(S)                                                            \
    do {                                                                      \
        bf16x8 a2 = {0, 0, 0, 0, 0, 0, 0, 0};                                 \
        if (g == 0) {                                                         \
            a2[0] = (short)(c4x##S & 0xffffu);                                \
            a2[1] = (short)(c4x##S >> 16);                                    \
            a2[2] = (short)(c4y##S & 0xffffu);                                \
        }                                                                     \
        _Pragma("unroll")                                                     \
        for (int nt = 0; nt < 4; ++nt) {                                      \
            float be = be##S[nt];                                             \
            f32x4 cc = {be, be, be, be};                                      \
            cc = __builtin_amdgcn_mfma_f32_16x16x32_bf16(a1##S, w1b[nt], cc, 0, 0, 0); \
            cc = __builtin_amdgcn_mfma_f32_16x16x32_bf16(a2, w1b[4 + nt], cc, 0, 0, 0); \
            _Pragma("unroll")                                                 \
            for (int q = 0; q < 4; ++q)                                       \
                *(float*)(h1p + wA[q * 2 + (nt & 1)] + (nt >> 1) * 128) =     \
                    fmaxf(cc[q], 0.f);                                        \
        }                                                                     \
        float4 q0 = *(const float4*)(h1p + rb0);                              \
        float4 q1 = *(const float4*)(h1p + rb1);                              \
        float4 q2 = *(const float4*)(h1p + rb0 + 128);                        \
        float4 q3 = *(const float4*)(h1p + rb1 + 128);                        \
        union { bf16x8 v; unsigned u[4]; } A30, A31;                          \
        A30.u[0] = pk2(q0.x, q0.y); A30.u[1] = pk2(q0.z, q0.w);               \
        A30.u[2] = pk2(q1.x, q1.y); A30.u[3] = pk2(q1.z, q1.w);               \
        A31.u[0] = pk2(q2.x, q2.y); A31.u[1] = pk2(q2.z, q2.w);               \
        A31.u[2] = pk2(q3.x, q3.y); A31.u[3] = pk2(q3.z, q3.w);               \
        float vmax[4];                                                        \
        _Pragma("unroll")                                                     \
        for (int nt = 0; nt < 4; ++nt) {                                      \
            bf16x8 wf0 = w2lds[nt * 64 + lane];                               \
            bf16x8 wf1 = w2lds[(4 + nt) * 64 + lane];                         \
            f32x4 cc = {b2v[nt], b2v[nt], b2v[nt], b2v[nt]};                  \
            cc = __builtin_amdgcn_mfma_f32_16x16x32_bf16(A30.v, wf0, cc, 0, 0, 0); \
            cc = __builtin_amdgcn_mfma_f32_16x16x32_bf16(A31.v, wf1, cc, 0, 0, 0); \
            vmax[nt] = fmaxf(fmaxf(cc[0], cc[1]), fmaxf(cc[2], cc[3]));       \
        }                                                                     \
        _Pragma("unroll")                                                     \
        for (int nt = 0; nt < 4; ++nt) {                                      \
            float v = vmax[nt];                                               \
            v = fmaxf(v, __shfl_xor(v, 16));                                  \
            v = fmaxf(v, __shfl_xor(v, 32));                                  \
            vmax[nt] = v;                                                     \
        }                                                                     \
        float outv = (g == 0) ? vmax[0] : (g == 1) ? vmax[1]                  \
                   : (g == 2) ? vmax[2] : vmax[3];                            \
        outv = fmaxf(outv, 0.f);                                              \
        atomicMax(&outI[(size_t)seg##S * COUT + lane], __float_as_int(outv)); \
    } while (0)

    LOADSLOT(0, t0);
    LOADSLOT(1, t0 + 1);
    LOADSLOT(2, t0 + 2);
    int tn = t0 + 3;
    int i = 0;
    for (;;) {
        if (i >= niter) break; COMPUTE(0); LOADSLOT(0, min(tn, ntiles - 1)); ++tn; ++i;
        if (i >= niter) break; COMPUTE(1); LOADSLOT(1, min(tn, ntiles - 1)); ++tn; ++i;
        if (i >= niter) break; COMPUTE(2); LOADSLOT(2, min(tn, ntiles - 1)); ++tn; ++i;
    }
#undef LOADSLOT
#undef COMPUTE
}

// ---------------------------------------------------------------------------
extern "C" void kernel_launch(void* const* d_in, const int* in_sizes, int n_in,
                              void* d_out, int out_size, void* d_ws, size_t ws_size,
                              hipStream_t stream) {
    const float* bxyz   = (const float*)d_in[0];
    const float* feat   = (const float*)d_in[1];
    const int*   sidx   = (const int*)d_in[2];
    const int*   e_pt   = (const int*)d_in[3];
    const int*   e_new  = (const int*)d_in[4];
    const float* W1     = (const float*)d_in[5];
    const float* b1     = (const float*)d_in[6];
    const float* W2     = (const float*)d_in[7];
    const float* b2     = (const float*)d_in[8];

    const int N = in_sizes[0] / 4;
    const int M = in_sizes[2];
    const int E = in_sizes[3];

    float* out_bxyz = (float*)d_out;                 // [M][4]
    float* out_feat = out_bxyz + (size_t)M * 4;      // [M][64]

    // ws layout (16B aligned regions)
    char*  ws        = (char*)d_ws;
    short* wpack     = (short*)ws;                                    // 16 KiB
    size_t off_cnt   = 16384;
    int*   counts    = (int*)(ws + off_cnt);                          // M
    size_t off_ts    = off_cnt + (((size_t)M * 4 + 15) & ~(size_t)15);
    int*   tstart    = (int*)(ws + off_ts);                           // M+4
    size_t off_sums  = off_ts + ((((size_t)M + 4) * 4 + 15) & ~(size_t)15);
    int*   sums      = (int*)(ws + off_sums);                         // 256
    size_t off_loc   = off_sums + 1024;
    int*   loc       = (int*)(ws + off_loc);                          // E
    size_t off_csr   = off_loc + (size_t)E * 4;
    size_t csr_cap   = (size_t)E + 15 * (size_t)M + 64;               // padded
    int*   csr_ep    = (int*)(ws + off_csr);
    size_t off_tseg  = off_csr + csr_cap * 4;
    int*   tile_seg  = (int*)(ws + off_tseg);                         // csr_cap/16
    size_t off_fb    = (off_tseg + (csr_cap / 16 + 64) * 4 + 63) & ~(size_t)63;
    uint4* featb     = (uint4*)(ws + off_fb);                         // N*80B
    int*   row1      = tstart + 1;

    int nbm     = (M + 255) / 256;
    int nbp     = (N + 255) / 256;
    int nbh     = (E / 8 + 255) / 256;
    int nchunks = (M + SCHUNK - 1) / SCHUNK;   // 123 for M=125000 (<=256 req.)
    int E8      = E / 8;

    hipMemsetAsync(counts, 0, (size_t)M * 4, stream);
    hipMemsetAsync(out_feat, 0, (size_t)M * COUT * 4, stream);

    prep_kernel<<<nbh + 32 + nbm + nbp, 256, 0, stream>>>(
        (const int4*)e_new, counts, (int4*)loc, E8,
        W1, W2, wpack, (const float4*)bxyz, sidx, (float4*)out_bxyz,
        feat, featb, M, N, nbh, nbm);

    scanA_kernel<<<nchunks, 256, 0, stream>>>(counts, row1, sums, M);
    scanC_kernel<<<nchunks, 256, 0, stream>>>(row1, sums, tstart, M);
    place_kernel<<<(E8 + 255) / 256, 256, 0, stream>>>(
        (const int4*)e_new, (const int4*)e_pt, (const int4*)loc,
        tstart, csr_ep, E8);
    padfill_kernel<<<(M + 255) / 256, 256, 0, stream>>>(
        counts, tstart, csr_ep, tile_seg, M);

    int maxtiles = E / 16 + M;                       // upper bound on tiles
    int nblocks  = (maxtiles + 4 * T_TILES - 1) / (4 * T_TILES);
    agg_kernel<<<nblocks, 256, 0, stream>>>(
        featb, csr_ep, tile_seg, tstart + M, (const bf16x8*)wpack,
        b1, b2, W1, (const float4*)out_bxyz, out_feat);
}

// Round 12
// 258.027 us; speedup vs baseline: 3.0753x; 1.0953x over previous
//
#include <hip/hip_runtime.h>
#include <hip/hip_bf16.h>

#define CIN 32
#define COUT 64
#define SCHUNK 1024
#define T_TILES 8

typedef __attribute__((ext_vector_type(8))) short bf16x8;
typedef __attribute__((ext_vector_type(4))) float f32x4;

__device__ inline short bf16r(float x) {
    unsigned u = __float_as_uint(x);
    return (short)((u + 0x7FFFu + ((u >> 16) & 1u)) >> 16);
}

__device__ inline unsigned pk2(float lo, float hi) {
    __hip_bfloat162 t = __float22bfloat162_rn(make_float2(lo, hi));
    return *(unsigned*)&t;
}

// ---------------------------------------------------------------------------
// Fused prep: [0,nbh) histloc ticketing | [+32) pack weights |
// [+nbm) gather out_bxyz | [+nbp) featb 64B rows + pbb 8B (bf16 pb.xyz).
__global__ void prep_kernel(const int4* __restrict__ e_new4,
                            int* __restrict__ counts,
                            int4* __restrict__ loc4, int E8,
                            const float* __restrict__ W1,
                            const float* __restrict__ W2,
                            short* __restrict__ wpack,
                            const float4* __restrict__ bxyz4,
                            const int* __restrict__ sidx,
                            float4* __restrict__ out_bxyz,
                            const float* __restrict__ feat,
                            uint4* __restrict__ featb,
                            uint2* __restrict__ pbb,
                            int M, int N, int nbh, int nbm) {
    int b = blockIdx.x, tid = threadIdx.x;
    if (b < nbh) {
        int i = b * 256 + tid;
        if (i >= E8) return;
        int4 a = e_new4[i * 2];
        int4 c = e_new4[i * 2 + 1];
        int4 la, lb;
        la.x = atomicAdd(&counts[a.x], 1);
        la.y = atomicAdd(&counts[a.y], 1);
        la.z = atomicAdd(&counts[a.z], 1);
        la.w = atomicAdd(&counts[a.w], 1);
        lb.x = atomicAdd(&counts[c.x], 1);
        lb.y = atomicAdd(&counts[c.y], 1);
        lb.z = atomicAdd(&counts[c.z], 1);
        lb.w = atomicAdd(&counts[c.w], 1);
        loc4[i * 2]     = la;
        loc4[i * 2 + 1] = lb;
    } else if (b < nbh + 32) {
        int t = (b - nbh) * 256 + tid;         // 8192 exactly
        int e = t & 7, l = (t >> 3) & 63, f = t >> 9;
        int g = l >> 4, n16 = l & 15;
        int kc = (f & 7) >> 2, nt = f & 3;
        int k = kc * 32 + g * 8 + e;
        int n = nt * 16 + n16;
        float v;
        if (f < 8) v = (k < CIN + 3) ? W1[k * COUT + n] : 0.f;
        else       v = W2[k * COUT + n];
        wpack[t] = bf16r(v);
    } else if (b < nbh + 32 + nbm) {
        int i = (b - nbh - 32) * 256 + tid;
        if (i < M) out_bxyz[i] = bxyz4[sidx[i]];
    } else {
        int p = (b - nbh - 32 - nbm) * 256 + tid;
        if (p < N) {
            const float4* s = (const float4*)(feat + (size_t)p * CIN);
            float4 f0 = s[0], f1 = s[1], f2 = s[2], f3 = s[3];
            float4 f4 = s[4], f5 = s[5], f6 = s[6], f7 = s[7];
            uint4* d = featb + (size_t)p * 4;
            d[0] = make_uint4(pk2(f0.x, f0.y), pk2(f0.z, f0.w), pk2(f1.x, f1.y), pk2(f1.z, f1.w));
            d[1] = make_uint4(pk2(f2.x, f2.y), pk2(f2.z, f2.w), pk2(f3.x, f3.y), pk2(f3.z, f3.w));
            d[2] = make_uint4(pk2(f4.x, f4.y), pk2(f4.z, f4.w), pk2(f5.x, f5.y), pk2(f5.z, f5.w));
            d[3] = make_uint4(pk2(f6.x, f6.y), pk2(f6.z, f6.w), pk2(f7.x, f7.y), pk2(f7.z, f7.w));
            float4 pb = bxyz4[p];
            pbb[p] = make_uint2(pk2(pb.y, pb.z), pk2(pb.w, 0.f));
        }
    }
}

// ---------------------------------------------------------------------------
// Scan of per-seg TILE counts ((cnt+15)/16) -> padded tile starts.
__global__ void scanA_kernel(const int* __restrict__ counts,
                             int* __restrict__ row1,
                             int* __restrict__ sums, int M) {
    __shared__ int lds[256];
    int t = threadIdx.x, blk = blockIdx.x;
    int base = blk * SCHUNK + t * 4;
    int v0 = (base + 0 < M) ? (counts[base + 0] + 15) >> 4 : 0;
    int v1 = (base + 1 < M) ? (counts[base + 1] + 15) >> 4 : 0;
    int v2 = (base + 2 < M) ? (counts[base + 2] + 15) >> 4 : 0;
    int v3 = (base + 3 < M) ? (counts[base + 3] + 15) >> 4 : 0;
    int s = v0 + v1 + v2 + v3;
    int val = s;
    lds[t] = val; __syncthreads();
    for (int off = 1; off < 256; off <<= 1) {
        int x = (t >= off) ? lds[t - off] : 0;
        __syncthreads();
        val += x; lds[t] = val;
        __syncthreads();
    }
    int ex = val - s;
    if (base + 0 < M) row1[base + 0] = ex + v0;
    if (base + 1 < M) row1[base + 1] = ex + v0 + v1;
    if (base + 2 < M) row1[base + 2] = ex + v0 + v1 + v2;
    if (base + 3 < M) row1[base + 3] = ex + s;
    if (t == 255) sums[blk] = val;
}

// scanC with scanB folded in (nchunks<=256).
__global__ void scanC_kernel(int* __restrict__ row1,
                             const int* __restrict__ sums,
                             int* __restrict__ tstart, int M) {
    __shared__ int lds[256];
    int blk = blockIdx.x, t = threadIdx.x;
    lds[t] = (t < blk) ? sums[t] : 0;
    __syncthreads();
    for (int off = 128; off > 0; off >>= 1) {
        if (t < off) lds[t] += lds[t + off];
        __syncthreads();
    }
    int off0 = lds[0];
    if (blk == 0 && t == 0) tstart[0] = 0;
    int base = blk * SCHUNK + t * 4;
#pragma unroll
    for (int i = 0; i < 4; ++i)
        if (base + i < M) row1[base + i] += off0;
}

// ---------------------------------------------------------------------------
// Placement + pad/meta fill: no atomics. Ticket-0 edge writes its segment's
// pad slots (self-duplicates, max-idempotent) and the per-tile segment ids.
__global__ void place_kernel(const int4* __restrict__ e_new4,
                             const int4* __restrict__ e_point4,
                             const int4* __restrict__ loc4,
                             const int* __restrict__ tstart,
                             const int* __restrict__ counts,
                             int* __restrict__ csr_ep,
                             int* __restrict__ tile_seg, int E8) {
    int i = blockIdx.x * blockDim.x + threadIdx.x;
    if (i >= E8) return;
    int4 n0 = e_new4[i * 2],   n1 = e_new4[i * 2 + 1];
    int4 p0 = e_point4[i * 2], p1 = e_point4[i * 2 + 1];
    int4 l0 = loc4[i * 2],     l1 = loc4[i * 2 + 1];
    int segs[8] = {n0.x, n0.y, n0.z, n0.w, n1.x, n1.y, n1.z, n1.w};
    int eps[8]  = {p0.x, p0.y, p0.z, p0.w, p1.x, p1.y, p1.z, p1.w};
    int locs[8] = {l0.x, l0.y, l0.z, l0.w, l1.x, l1.y, l1.z, l1.w};
#pragma unroll
    for (int k = 0; k < 8; ++k) {
        int seg = segs[k], ep = eps[k], lc = locs[k];
        int tst  = tstart[seg];
        int prow = tst * 16;
        csr_ep[prow + lc] = ep;
        if (lc == 0) {
            int cnt = counts[seg];
            int ntl = (cnt + 15) >> 4;
            for (int j = cnt; j < ntl * 16; ++j) csr_ep[prow + j] = ep;
            for (int j = 0; j < ntl; ++j) tile_seg[tst + j] = seg;
        }
    }
}

// ---------------------------------------------------------------------------
// Aggregation: wave wid owns tiles [wid*T, wid*T+T); independent idempotent
// tiles ending in one wave-coalesced atomicMax row. 2-slot ping-pong prefetch;
// w2 fragments in block-shared LDS; transpose swizzle X(row)=(row&7)<<4.
__global__ __launch_bounds__(256)
void agg_kernel(const uint4* __restrict__ featb,    // [N][4] 64B rows
                const uint2* __restrict__ pbb,      // [N] bf16 xyz
                const int* __restrict__ csr_ep,     // padded
                const int* __restrict__ tile_seg,   // [ntiles]
                const int* __restrict__ ntiles_ptr, // = &tstart[M]
                const bf16x8* __restrict__ wpack,
                const float* __restrict__ b1,
                const float* __restrict__ b2,
                const float* __restrict__ W1,
                const float4* __restrict__ new_bxyz4,
                float* __restrict__ out_feat) {
    __shared__ char   h1buf[4][4096];
    __shared__ bf16x8 w2lds[512];     // 8 KB block-shared

    const int ntiles = ntiles_ptr[0];
    if (blockIdx.x * 4 * T_TILES >= ntiles) return;   // whole block idle

    w2lds[threadIdx.x]       = wpack[512 + threadIdx.x];
    w2lds[threadIdx.x + 256] = wpack[768 + threadIdx.x];
    __syncthreads();

    const int lane = threadIdx.x & 63;
    const int w    = threadIdx.x >> 6;
    const int m    = lane & 15;
    const int g    = lane >> 4;

    int wid = blockIdx.x * 4 + w;
    int t0  = wid * T_TILES;
    int niter = min(T_TILES, ntiles - t0);
    if (niter <= 0) return;

    bf16x8 w1b[8];
#pragma unroll
    for (int f = 0; f < 8; ++f) w1b[f] = wpack[f * 64 + lane];

    float b1v[4], b2v[4], w1r0[4], w1r1[4], w1r2[4];
#pragma unroll
    for (int nt = 0; nt < 4; ++nt) {
        int col = nt * 16 + m;
        b1v[nt]  = b1[col];
        b2v[nt]  = b2[col];
        w1r0[nt] = W1[32 * COUT + col];
        w1r1[nt] = W1[33 * COUT + col];
        w1r2[nt] = W1[34 * COUT + col];
    }

    char* h1p = h1buf[w];
    int wA[8];
#pragma unroll
    for (int q = 0; q < 4; ++q) {
        int row = g * 4 + q;
        int kk = (row & 7) << 4;
        wA[q * 2 + 0] = (row * 256 + m * 4) ^ kk;
        wA[q * 2 + 1] = (row * 256 + (m + 16) * 4) ^ kk;
    }
    const int frm = (m & 7) << 4;
    const int rb0 = (m * 256 + g * 32) ^ frm;
    const int rb1 = (m * 256 + g * 32 + 16) ^ frm;

    int* outI = (int*)out_feat;

    int seg0, seg1;
    bf16x8 a10, a11;
    unsigned c4x0, c4y0, c4x1, c4y1;
    float be0[4], be1[4];

#define LOADSLOT(S, TI)                                                       \
    do {                                                                      \
        int ti_ = min((TI), ntiles - 1);                                      \
        seg##S = tile_seg[ti_];                                               \
        int ep_ = csr_ep[ti_ * 16 + m];                                       \
        a1##S = ((const bf16x8*)featb)[(size_t)(unsigned)ep_ * 4 + g];        \
        uint2 c_ = pbb[(unsigned)ep_];                                        \
        c4x##S = c_.x; c4y##S = c_.y;                                         \
        float4 nb_ = new_bxyz4[seg##S];                                       \
        _Pragma("unroll")                                                     \
        for (int nt = 0; nt < 4; ++nt)                                        \
            be##S[nt] = b1v[nt] - nb_.y * w1r0[nt] - nb_.z * w1r1[nt]         \
                                 - nb_.w * w1r2[nt];                          \
    } while (0)

#define COMPUTE(S)                                                            \
    do {                                                                      \
        bf16x8 a2 = {0, 0, 0, 0, 0, 0, 0, 0};                                 \
        if (g == 0) {                                                         \
            a2[0] = (short)(c4x##S & 0xffffu);                                \
            a2[1] = (short)(c4x##S >> 16);                                    \
            a2[2] = (short)(c4y##S & 0xffffu);                                \
        }                                                                     \
        _Pragma("unroll")                                                     \
        for (int nt = 0; nt < 4; ++nt) {                                      \
            float be = be##S[nt];                                             \
            f32x4 cc = {be, be, be, be};                                      \
            cc = __builtin_amdgcn_mfma_f32_16x16x32_bf16(a1##S, w1b[nt], cc, 0, 0, 0); \
            cc = __builtin_amdgcn_mfma_f32_16x16x32_bf16(a2, w1b[4 + nt], cc, 0, 0, 0); \
            _Pragma("unroll")                                                 \
            for (int q = 0; q < 4; ++q)                                       \
                *(float*)(h1p + wA[q * 2 + (nt & 1)] + (nt >> 1) * 128) =     \
                    fmaxf(cc[q], 0.f);                                        \
        }                                                                     \
        float4 q0 = *(const float4*)(h1p + rb0);                              \
        float4 q1 = *(const float4*)(h1p + rb1);                              \
        float4 q2 = *(const float4*)(h1p + rb0 + 128);                        \
        float4 q3 = *(const float4*)(h1p + rb1 + 128);                        \
        union { bf16x8 v; unsigned u[4]; } A30, A31;                          \
        A30.u[0] = pk2(q0.x, q0.y); A30.u[1] = pk2(q0.z, q0.w);               \
        A30.u[2] = pk2(q1.x, q1.y); A30.u[3] = pk2(q1.z, q1.w);               \
        A31.u[0] = pk2(q2.x, q2.y); A31.u[1] = pk2(q2.z, q2.w);               \
        A31.u[2] = pk2(q3.x, q3.y); A31.u[3] = pk2(q3.z, q3.w);               \
        float vmax[4];                                                        \
        _Pragma("unroll")                                                     \
        for (int nt = 0; nt < 4; ++nt) {                                      \
            bf16x8 wf0 = w2lds[nt * 64 + lane];                               \
            bf16x8 wf1 = w2lds[(4 + nt) * 64 + lane];                         \
            f32x4 cc = {b2v[nt], b2v[nt], b2v[nt], b2v[nt]};                  \
            cc = __builtin_amdgcn_mfma_f32_16x16x32_bf16(A30.v, wf0, cc, 0, 0, 0); \
            cc = __builtin_amdgcn_mfma_f32_16x16x32_bf16(A31.v, wf1, cc, 0, 0, 0); \
            vmax[nt] = fmaxf(fmaxf(cc[0], cc[1]), fmaxf(cc[2], cc[3]));       \
        }                                                                     \
        _Pragma("unroll")                                                     \
        for (int nt = 0; nt < 4; ++nt) {                                      \
            float v = vmax[nt];                                               \
            v = fmaxf(v, __shfl_xor(v, 16));                                  \
            v = fmaxf(v, __shfl_xor(v, 32));                                  \
            vmax[nt] = v;                                                     \
        }                                                                     \
        float outv = (g == 0) ? vmax[0] : (g == 1) ? vmax[1]                  \
                   : (g == 2) ? vmax[2] : vmax[3];                            \
        outv = fmaxf(outv, 0.f);                                              \
        atomicMax(&outI[(size_t)seg##S * COUT + lane], __float_as_int(outv)); \
    } while (0)

    LOADSLOT(0, t0);
    int i = 0;
    for (;;) {
        if (i >= niter) break;
        LOADSLOT(1, t0 + i + 1);
        COMPUTE(0); ++i;
        if (i >= niter) break;
        LOADSLOT(0, t0 + i + 1);
        COMPUTE(1); ++i;
    }
#undef LOADSLOT
#undef COMPUTE
}

// ---------------------------------------------------------------------------
extern "C" void kernel_launch(void* const* d_in, const int* in_sizes, int n_in,
                              void* d_out, int out_size, void* d_ws, size_t ws_size,
                              hipStream_t stream) {
    const float* bxyz   = (const float*)d_in[0];
    const float* feat   = (const float*)d_in[1];
    const int*   sidx   = (const int*)d_in[2];
    const int*   e_pt   = (const int*)d_in[3];
    const int*   e_new  = (const int*)d_in[4];
    const float* W1     = (const float*)d_in[5];
    const float* b1     = (const float*)d_in[6];
    const float* W2     = (const float*)d_in[7];
    const float* b2     = (const float*)d_in[8];

    const int N = in_sizes[0] / 4;
    const int M = in_sizes[2];
    const int E = in_sizes[3];

    float* out_bxyz = (float*)d_out;                 // [M][4]
    float* out_feat = out_bxyz + (size_t)M * 4;      // [M][64]

    // ws layout (16B aligned regions)
    char*  ws        = (char*)d_ws;
    short* wpack     = (short*)ws;                                    // 16 KiB
    size_t off_cnt   = 16384;
    int*   counts    = (int*)(ws + off_cnt);                          // M
    size_t off_ts    = off_cnt + (((size_t)M * 4 + 15) & ~(size_t)15);
    int*   tstart    = (int*)(ws + off_ts);                           // M+4
    size_t off_sums  = off_ts + ((((size_t)M + 4) * 4 + 15) & ~(size_t)15);
    int*   sums      = (int*)(ws + off_sums);                         // 256
    size_t off_loc   = off_sums + 1024;
    int*   loc       = (int*)(ws + off_loc);                          // E
    size_t off_csr   = off_loc + (size_t)E * 4;
    size_t csr_cap   = (size_t)E + 15 * (size_t)M + 64;               // padded
    int*   csr_ep    = (int*)(ws + off_csr);
    size_t off_tseg  = off_csr + csr_cap * 4;
    int*   tile_seg  = (int*)(ws + off_tseg);                         // csr_cap/16
    size_t off_pbb   = (off_tseg + (csr_cap / 16 + 64) * 4 + 63) & ~(size_t)63;
    uint2* pbb       = (uint2*)(ws + off_pbb);                        // N*8B
    size_t off_fb    = (off_pbb + (size_t)N * 8 + 63) & ~(size_t)63;
    uint4* featb     = (uint4*)(ws + off_fb);                         // N*64B
    int*   row1      = tstart + 1;

    int nbm     = (M + 255) / 256;
    int nbp     = (N + 255) / 256;
    int nbh     = (E / 8 + 255) / 256;
    int nchunks = (M + SCHUNK - 1) / SCHUNK;   // 123 for M=125000 (<=256 req.)
    int E8      = E / 8;

    hipMemsetAsync(counts, 0, (size_t)M * 4, stream);
    hipMemsetAsync(out_feat, 0, (size_t)M * COUT * 4, stream);

    prep_kernel<<<nbh + 32 + nbm + nbp, 256, 0, stream>>>(
        (const int4*)e_new, counts, (int4*)loc, E8,
        W1, W2, wpack, (const float4*)bxyz, sidx, (float4*)out_bxyz,
        feat, featb, pbb, M, N, nbh, nbm);

    scanA_kernel<<<nchunks, 256, 0, stream>>>(counts, row1, sums, M);
    scanC_kernel<<<nchunks, 256, 0, stream>>>(row1, sums, tstart, M);
    place_kernel<<<(E8 + 255) / 256, 256, 0, stream>>>(
        (const int4*)e_new, (const int4*)e_pt, (const int4*)loc,
        tstart, counts, csr_ep, tile_seg, E8);

    int maxtiles = E / 16 + M;                       // upper bound on tiles
    int nblocks  = (maxtiles + 4 * T_TILES - 1) / (4 * T_TILES);
    agg_kernel<<<nblocks, 256, 0, stream>>>(
        featb, pbb, csr_ep, tile_seg, tstart + M, (const bf16x8*)wpack,
        b1, b2, W1, (const float4*)out_bxyz, out_feat);
}